// Round 6
// baseline (843.718 us; speedup 1.0000x reference)
//
#include <hip/hip_runtime.h>

// VQ-VAE Vector Quantizer: N=65536 rows, K=4096 codes, D=64, fp32.
// R8: 2 rows per lane on top of R7's VMEM-broadcast pipelined e-feed.
// R7 measured: VALUBusy 72%, scan 457us. Residual stall: per-iter own-wave
// slack (~148cy) < L2 latency (~250cy) and 4 waves/SIMD can't cover. Fix:
// each lane scans TWO z rows (n, n+256) against the same e-stream ->
// per-iter issue time ~280cy > L2 latency (self-hiding prefetch), e-traffic
// per FLOP halved, overhead fraction halved. Regs ~215 -> 2 waves/SIMD via
// __launch_bounds__(256,2); prefetch slack now exceeds latency so low
// occupancy is sufficient.
// Per-row FMA sequence is bit-identical to the R0/R7 passing kernels
// (quad-split partials by d mod 4, ascending d, (s0+s1)+(s2+s3),
// dist = (z2 + e2[k]) - 2*dot, strict < first-index tie-break); rows never
// mix (fmaf chains are serially data-dependent, no reassociation without
// fast-math) => identical indices, absmax 0 by construction.
//
// out layout (float): [0,N*D) z_q_st | [ND] vq | [ND+1] cb | [ND+2] cm |
//                     [ND+3, ND+3+N) indices | [ND+3+N] perplexity | [ND+4+N] active

constexpr int N = 65536;
constexpr int K = 4096;
constexpr int D = 64;
constexpr int S = 8;      // K-split
constexpr int KS = K / S; // 512 codes per slice

__global__ __launch_bounds__(256) void prep_kernel(const float* __restrict__ emb,
                                                   float* __restrict__ e2,
                                                   int* __restrict__ counts,
                                                   float* __restrict__ loss) {
  int k = blockIdx.x * 256 + threadIdx.x;
  if (k < K) {
    const float4* ep = (const float4*)(emb + (size_t)k * D);
    float s0 = 0.f, s1 = 0.f, s2 = 0.f, s3 = 0.f;
#pragma unroll
    for (int i = 0; i < 16; ++i) {
      float4 e = ep[i];
      s0 = fmaf(e.x, e.x, s0);
      s1 = fmaf(e.y, e.y, s1);
      s2 = fmaf(e.z, e.z, s2);
      s3 = fmaf(e.w, e.w, s3);
    }
    e2[k] = (s0 + s1) + (s2 + s3);
    counts[k] = 0;
  }
  if (blockIdx.x == 0 && threadIdx.x == 0) *loss = 0.0f;
}

// Scan one K-slice for 512 rows per block (2 per lane). grid = (N/512, S).
__global__ __launch_bounds__(256, 2) void vq_scan(const float* __restrict__ z,
                                                  const float* __restrict__ emb,
                                                  const float* __restrict__ e2,
                                                  float* __restrict__ pbest,
                                                  int* __restrict__ pidx) {
  const int tid = threadIdx.x;
  const int s = blockIdx.y;
  const int k0 = s * KS;
  const int n0 = blockIdx.x * 512 + tid;   // row A
  const int n1 = n0 + 256;                 // row B

  // Two z rows per lane, register-resident.
  float4 za[16], zb[16];
  {
    const float4* zpa = (const float4*)(z + (size_t)n0 * D);
    const float4* zpb = (const float4*)(z + (size_t)n1 * D);
#pragma unroll
    for (int i = 0; i < 16; ++i) za[i] = zpa[i];
#pragma unroll
    for (int i = 0; i < 16; ++i) zb[i] = zpb[i];
  }

  // z2 per row, same instruction sequence as R0/R7 (quad-split, ascending d).
  float z2a, z2b;
  {
    float s0 = 0.f, s1 = 0.f, s2 = 0.f, s3 = 0.f;
#pragma unroll
    for (int i = 0; i < 16; ++i) {
      s0 = fmaf(za[i].x, za[i].x, s0);
      s1 = fmaf(za[i].y, za[i].y, s1);
      s2 = fmaf(za[i].z, za[i].z, s2);
      s3 = fmaf(za[i].w, za[i].w, s3);
    }
    z2a = (s0 + s1) + (s2 + s3);
  }
  {
    float s0 = 0.f, s1 = 0.f, s2 = 0.f, s3 = 0.f;
#pragma unroll
    for (int i = 0; i < 16; ++i) {
      s0 = fmaf(zb[i].x, zb[i].x, s0);
      s1 = fmaf(zb[i].y, zb[i].y, s1);
      s2 = fmaf(zb[i].z, zb[i].z, s2);
      s3 = fmaf(zb[i].w, zb[i].w, s3);
    }
    z2b = (s0 + s1) + (s2 + s3);
  }

  // Flat float4 stream of this slice's codebook: code k = fp[16k .. 16k+15].
  const float4* fp = (const float4*)(emb + (size_t)k0 * D);
  const float* e2p = e2 + k0;

  // Prologue: preload code 0 into the two banks (f=0..7 -> rr, f=8..15 -> qq).
  float4 rr[8], qq[8];
#pragma unroll
  for (int j = 0; j < 8; ++j) rr[j] = fp[j];
#pragma unroll
  for (int j = 0; j < 8; ++j) qq[j] = fp[8 + j];
  float e2cur = e2p[0];

  float bestA = 3.4e38f, bestB = 3.4e38f;
  int idxA = k0, idxB = k0;

  for (int k = 0; k < KS; ++k) {
    const int kn = (k + 1 < KS) ? (k + 1) : (KS - 1);  // clamped (last prefetch dead)
    const float4* fn = fp + (size_t)kn * 16;

    float a0 = 0.f, a1 = 0.f, a2 = 0.f, a3 = 0.f;
    float b0 = 0.f, b1 = 0.f, b2 = 0.f, b3 = 0.f;
    // Phase 1: consume rr (f=0..7 of code k) for both rows, refill with code kn.
#pragma unroll
    for (int j = 0; j < 8; ++j) {
      float4 e = rr[j];
      // d = 4*j + {0,1,2,3}; partial sN takes d%4==N, ascending d (per row)
      a0 = fmaf(za[j].x, e.x, a0);
      a1 = fmaf(za[j].y, e.y, a1);
      a2 = fmaf(za[j].z, e.z, a2);
      a3 = fmaf(za[j].w, e.w, a3);
      b0 = fmaf(zb[j].x, e.x, b0);
      b1 = fmaf(zb[j].y, e.y, b1);
      b2 = fmaf(zb[j].z, e.z, b2);
      b3 = fmaf(zb[j].w, e.w, b3);
      rr[j] = fn[j];  // WAR: issues after both rows consumed e
    }
    float e2n = e2p[kn];
    // Phase 2: consume qq (f=8..15 of code k), refill with code kn.
#pragma unroll
    for (int j = 0; j < 8; ++j) {
      float4 e = qq[j];
      a0 = fmaf(za[8 + j].x, e.x, a0);
      a1 = fmaf(za[8 + j].y, e.y, a1);
      a2 = fmaf(za[8 + j].z, e.z, a2);
      a3 = fmaf(za[8 + j].w, e.w, a3);
      b0 = fmaf(zb[8 + j].x, e.x, b0);
      b1 = fmaf(zb[8 + j].y, e.y, b1);
      b2 = fmaf(zb[8 + j].z, e.z, b2);
      b3 = fmaf(zb[8 + j].w, e.w, b3);
      qq[j] = fn[8 + j];
    }
    float dotA = (a0 + a1) + (a2 + a3);
    float distA = (z2a + e2cur) - 2.0f * dotA;  // reference fp32 rounding replicated
    if (distA < bestA) { bestA = distA; idxA = k0 + k; }  // strict <: first index
    float dotB = (b0 + b1) + (b2 + b3);
    float distB = (z2b + e2cur) - 2.0f * dotB;
    if (distB < bestB) { bestB = distB; idxB = k0 + k; }
    e2cur = e2n;
  }

  pbest[(size_t)s * N + n0] = bestA;
  pidx[(size_t)s * N + n0] = idxA;
  pbest[(size_t)s * N + n1] = bestB;
  pidx[(size_t)s * N + n1] = idxB;
}

// Combine slices (ascending s = ascending k => first-index tie-break preserved),
// then gather/losses/counts/index write.
__global__ __launch_bounds__(256) void vq_epilogue(const float* __restrict__ z,
                                                   const float* __restrict__ emb,
                                                   const float* __restrict__ pbest,
                                                   const int* __restrict__ pidx,
                                                   float* __restrict__ out,
                                                   int* __restrict__ counts,
                                                   float* __restrict__ loss) {
  __shared__ float red[4];
  const int tid = threadIdx.x;
  const int n = blockIdx.x * 256 + tid;

  float best = pbest[n];
  int bidx = pidx[n];
#pragma unroll
  for (int s = 1; s < S; ++s) {
    float d = pbest[(size_t)s * N + n];
    if (d < best) { best = d; bidx = pidx[(size_t)s * N + n]; }
  }

  out[(size_t)N * D + 3 + n] = (float)bidx;
  atomicAdd(&counts[bidx], 1);

  const float4* zp = (const float4*)(z + (size_t)n * D);
  const float4* qp = (const float4*)(emb + (size_t)bidx * D);
  float4* op = (float4*)(out + (size_t)n * D);
  float lsum = 0.f;
#pragma unroll
  for (int i = 0; i < 16; ++i) {
    float4 q = qp[i];
    float4 zz = zp[i];
    float dx = q.x - zz.x, dy = q.y - zz.y, dz = q.z - zz.z, dw = q.w - zz.w;
    lsum = fmaf(dx, dx, lsum);
    lsum = fmaf(dy, dy, lsum);
    lsum = fmaf(dz, dz, lsum);
    lsum = fmaf(dw, dw, lsum);
    // z_q_st = z + (z_q - z), replicated op-for-op
    float4 r;
    r.x = zz.x + dx; r.y = zz.y + dy; r.z = zz.z + dz; r.w = zz.w + dw;
    op[i] = r;
  }

#pragma unroll
  for (int off = 32; off > 0; off >>= 1) lsum += __shfl_down(lsum, off);
  if ((tid & 63) == 0) red[tid >> 6] = lsum;
  __syncthreads();
  if (tid == 0) atomicAdd(loss, (red[0] + red[1]) + (red[2] + red[3]));
}

__global__ __launch_bounds__(256) void finalize_kernel(const int* __restrict__ counts,
                                                       const float* __restrict__ loss,
                                                       float* __restrict__ out) {
  const int tid = threadIdx.x;
  double ent = 0.0;
  int active = 0;
  for (int k = tid; k < K; k += 256) {
    int c = counts[k];
    float p = (float)c / 65536.0f;
    if (c > 0) active++;
    ent += (double)(p * logf(p + 1e-10f));
  }
#pragma unroll
  for (int off = 32; off > 0; off >>= 1) {
    ent += __shfl_down(ent, off);
    active += __shfl_down(active, off);
  }
  __shared__ double ered[4];
  __shared__ int ared[4];
  if ((tid & 63) == 0) { ered[tid >> 6] = ent; ared[tid >> 6] = active; }
  __syncthreads();
  if (tid == 0) {
    double e = (ered[0] + ered[1]) + (ered[2] + ered[3]);
    int a = (ared[0] + ared[1]) + (ared[2] + ared[3]);
    float mean = *loss / (float)((size_t)N * D);
    float cb = mean;
    float cm = mean;
    float vq = cb + 0.25f * cm;
    size_t base = (size_t)N * D;
    out[base + 0] = vq;
    out[base + 1] = cb;
    out[base + 2] = cm;
    out[base + 3 + N] = (float)exp(-e);
    out[base + 4 + N] = (float)a;
  }
}

extern "C" void kernel_launch(void* const* d_in, const int* in_sizes, int n_in,
                              void* d_out, int out_size, void* d_ws, size_t ws_size,
                              hipStream_t stream) {
  const float* z = (const float*)d_in[0];
  const float* emb = (const float*)d_in[1];
  float* out = (float*)d_out;

  char* w = (char*)d_ws;
  float* e2 = (float*)w;                         w += (size_t)K * sizeof(float);
  int* counts = (int*)w;                         w += (size_t)K * sizeof(int);
  float* loss = (float*)w;                       w += 256;  // keep alignment
  float* pbest = (float*)w;                      w += (size_t)S * N * sizeof(float);
  int* pidx = (int*)w;

  prep_kernel<<<K / 256, 256, 0, stream>>>(emb, e2, counts, loss);
  vq_scan<<<dim3(N / 512, S), 256, 0, stream>>>(z, emb, e2, pbest, pidx);
  vq_epilogue<<<N / 256, 256, 0, stream>>>(z, emb, pbest, pidx, out, counts, loss);
  finalize_kernel<<<1, 256, 0, stream>>>(counts, loss, out);
}

// Round 7
// 488.268 us; speedup vs baseline: 1.7280x; 1.7280x over previous
//
#include <hip/hip_runtime.h>

// VQ-VAE Vector Quantizer: N=65536 rows, K=4096 codes, D=64, fp32.
// R9: address-lean e-feed. R7 measured 457us @ VALUBusy 72% => VALU-busy time
// 329us == ~100 VALU ops/code vs the 74 the algorithm needs. The fat is
// per-iteration 64-bit address math for the 17 VMEM loads: R7's clamped
// prefetch base (kn = k+1<KS ? k+1 : KS-1) defeats pointer strength
// reduction. Fix: running pointer fc += 16/iter, all e-loads at fc[16+j] /
// fc[24+j] (byte offsets 256..496 -> fold into global_load's 13-bit signed
// immediate), last code peeled into a no-refill epilogue. R8's 2-row variant
// spilled (WRITE_SIZE 4->21MB at VGPR cap 128) and is reverted.
// FMA sequence per (row,code) is bit-identical to the R0/R7 passing kernels
// (quad-split partials by d mod 4, ascending d, (s0+s1)+(s2+s3),
// dist = (z2 + e2[k]) - 2*dot, strict < first-index tie-break) => identical
// indices, absmax 0 by construction.
//
// out layout (float): [0,N*D) z_q_st | [ND] vq | [ND+1] cb | [ND+2] cm |
//                     [ND+3, ND+3+N) indices | [ND+3+N] perplexity | [ND+4+N] active

constexpr int N = 65536;
constexpr int K = 4096;
constexpr int D = 64;
constexpr int S = 8;      // K-split: grid = 2048 blocks
constexpr int KS = K / S; // 512 codes per slice

__global__ __launch_bounds__(256) void prep_kernel(const float* __restrict__ emb,
                                                   float* __restrict__ e2,
                                                   int* __restrict__ counts,
                                                   float* __restrict__ loss) {
  int k = blockIdx.x * 256 + threadIdx.x;
  if (k < K) {
    const float4* ep = (const float4*)(emb + (size_t)k * D);
    float s0 = 0.f, s1 = 0.f, s2 = 0.f, s3 = 0.f;
#pragma unroll
    for (int i = 0; i < 16; ++i) {
      float4 e = ep[i];
      s0 = fmaf(e.x, e.x, s0);
      s1 = fmaf(e.y, e.y, s1);
      s2 = fmaf(e.z, e.z, s2);
      s3 = fmaf(e.w, e.w, s3);
    }
    e2[k] = (s0 + s1) + (s2 + s3);
    counts[k] = 0;
  }
  if (blockIdx.x == 0 && threadIdx.x == 0) *loss = 0.0f;
}

// Scan one K-slice for 256 rows per block. grid = (N/256, S). No LDS.
__global__ __launch_bounds__(256) void vq_scan(const float* __restrict__ z,
                                               const float* __restrict__ emb,
                                               const float* __restrict__ e2,
                                               float* __restrict__ pbest,
                                               int* __restrict__ pidx) {
  const int tid = threadIdx.x;
  const int n = blockIdx.x * 256 + tid;
  const int s = blockIdx.y;
  const int k0 = s * KS;

  // This lane's z row (register/AGPR-resident on the unified file).
  float4 zr[16];
  {
    const float4* zp = (const float4*)(z + (size_t)n * D);
#pragma unroll
    for (int i = 0; i < 16; ++i) zr[i] = zp[i];
  }

  // z2, same instruction sequence as R0/R7 (quad-split by d mod 4, ascending d).
  float z2;
  {
    float s0 = 0.f, s1 = 0.f, s2 = 0.f, s3 = 0.f;
#pragma unroll
    for (int i = 0; i < 16; ++i) {
      s0 = fmaf(zr[i].x, zr[i].x, s0);
      s1 = fmaf(zr[i].y, zr[i].y, s1);
      s2 = fmaf(zr[i].z, zr[i].z, s2);
      s3 = fmaf(zr[i].w, zr[i].w, s3);
    }
    z2 = (s0 + s1) + (s2 + s3);
  }

  // Running pointers: ONE 64-bit bump each per iteration; every load in the
  // body uses a compile-time offset that folds into the VMEM immediate.
  const float4* fc = (const float4*)(emb + (size_t)k0 * D);  // current code
  const float* e2c = e2 + k0;

  // Prologue: preload code 0 into the two banks (f=0..7 -> rr, f=8..15 -> qq).
  float4 rr[8], qq[8];
#pragma unroll
  for (int j = 0; j < 8; ++j) rr[j] = fc[j];
#pragma unroll
  for (int j = 0; j < 8; ++j) qq[j] = fc[8 + j];
  float e2cur = e2c[0];

  float best = 3.4e38f;
  int bidx = k0;

  for (int k = 0; k < KS - 1; ++k) {
    float s0 = 0.f, s1 = 0.f, s2 = 0.f, s3 = 0.f;
    // Phase 1: consume rr (f=0..7 of code k), refill with code k+1.
    // Refill addresses: fc[16+j] -> imm offset 256+16j (folds, no VALU).
#pragma unroll
    for (int j = 0; j < 8; ++j) {
      float4 e = rr[j];
      // d = 4*j + {0,1,2,3}; partial sN takes d%4==N, ascending d
      s0 = fmaf(zr[j].x, e.x, s0);
      s1 = fmaf(zr[j].y, e.y, s1);
      s2 = fmaf(zr[j].z, e.z, s2);
      s3 = fmaf(zr[j].w, e.w, s3);
      rr[j] = fc[16 + j];  // WAR: legal only after the FMAs above
    }
    float e2n = e2c[1];
    // Phase 2: consume qq (f=8..15 of code k), refill with code k+1.
#pragma unroll
    for (int j = 0; j < 8; ++j) {
      float4 e = qq[j];
      s0 = fmaf(zr[8 + j].x, e.x, s0);
      s1 = fmaf(zr[8 + j].y, e.y, s1);
      s2 = fmaf(zr[8 + j].z, e.z, s2);
      s3 = fmaf(zr[8 + j].w, e.w, s3);
      qq[j] = fc[24 + j];  // imm offset 384+16j
    }
    float dot = (s0 + s1) + (s2 + s3);
    float dist = (z2 + e2cur) - 2.0f * dot;  // reference fp32 rounding replicated
    if (dist < best) { best = dist; bidx = k0 + k; }  // strict <: first-index in slice
    e2cur = e2n;
    fc += 16;
    e2c += 1;
  }
  {
    // Final code (k = KS-1): identical FMA sequence, no refill.
    float s0 = 0.f, s1 = 0.f, s2 = 0.f, s3 = 0.f;
#pragma unroll
    for (int j = 0; j < 8; ++j) {
      float4 e = rr[j];
      s0 = fmaf(zr[j].x, e.x, s0);
      s1 = fmaf(zr[j].y, e.y, s1);
      s2 = fmaf(zr[j].z, e.z, s2);
      s3 = fmaf(zr[j].w, e.w, s3);
    }
#pragma unroll
    for (int j = 0; j < 8; ++j) {
      float4 e = qq[j];
      s0 = fmaf(zr[8 + j].x, e.x, s0);
      s1 = fmaf(zr[8 + j].y, e.y, s1);
      s2 = fmaf(zr[8 + j].z, e.z, s2);
      s3 = fmaf(zr[8 + j].w, e.w, s3);
    }
    float dot = (s0 + s1) + (s2 + s3);
    float dist = (z2 + e2cur) - 2.0f * dot;
    if (dist < best) { best = dist; bidx = k0 + KS - 1; }
  }

  pbest[(size_t)s * N + n] = best;
  pidx[(size_t)s * N + n] = bidx;
}

// Combine slices (ascending s = ascending k => first-index tie-break preserved),
// then gather/losses/counts/index write.
__global__ __launch_bounds__(256) void vq_epilogue(const float* __restrict__ z,
                                                   const float* __restrict__ emb,
                                                   const float* __restrict__ pbest,
                                                   const int* __restrict__ pidx,
                                                   float* __restrict__ out,
                                                   int* __restrict__ counts,
                                                   float* __restrict__ loss) {
  __shared__ float red[4];
  const int tid = threadIdx.x;
  const int n = blockIdx.x * 256 + tid;

  float best = pbest[n];
  int bidx = pidx[n];
#pragma unroll
  for (int s = 1; s < S; ++s) {
    float d = pbest[(size_t)s * N + n];
    if (d < best) { best = d; bidx = pidx[(size_t)s * N + n]; }
  }

  out[(size_t)N * D + 3 + n] = (float)bidx;
  atomicAdd(&counts[bidx], 1);

  const float4* zp = (const float4*)(z + (size_t)n * D);
  const float4* qp = (const float4*)(emb + (size_t)bidx * D);
  float4* op = (float4*)(out + (size_t)n * D);
  float lsum = 0.f;
#pragma unroll
  for (int i = 0; i < 16; ++i) {
    float4 q = qp[i];
    float4 zz = zp[i];
    float dx = q.x - zz.x, dy = q.y - zz.y, dz = q.z - zz.z, dw = q.w - zz.w;
    lsum = fmaf(dx, dx, lsum);
    lsum = fmaf(dy, dy, lsum);
    lsum = fmaf(dz, dz, lsum);
    lsum = fmaf(dw, dw, lsum);
    // z_q_st = z + (z_q - z), replicated op-for-op
    float4 r;
    r.x = zz.x + dx; r.y = zz.y + dy; r.z = zz.z + dz; r.w = zz.w + dw;
    op[i] = r;
  }

#pragma unroll
  for (int off = 32; off > 0; off >>= 1) lsum += __shfl_down(lsum, off);
  if ((tid & 63) == 0) red[tid >> 6] = lsum;
  __syncthreads();
  if (tid == 0) atomicAdd(loss, (red[0] + red[1]) + (red[2] + red[3]));
}

__global__ __launch_bounds__(256) void finalize_kernel(const int* __restrict__ counts,
                                                       const float* __restrict__ loss,
                                                       float* __restrict__ out) {
  const int tid = threadIdx.x;
  double ent = 0.0;
  int active = 0;
  for (int k = tid; k < K; k += 256) {
    int c = counts[k];
    float p = (float)c / 65536.0f;
    if (c > 0) active++;
    ent += (double)(p * logf(p + 1e-10f));
  }
#pragma unroll
  for (int off = 32; off > 0; off >>= 1) {
    ent += __shfl_down(ent, off);
    active += __shfl_down(active, off);
  }
  __shared__ double ered[4];
  __shared__ int ared[4];
  if ((tid & 63) == 0) { ered[tid >> 6] = ent; ared[tid >> 6] = active; }
  __syncthreads();
  if (tid == 0) {
    double e = (ered[0] + ered[1]) + (ered[2] + ered[3]);
    int a = (ared[0] + ared[1]) + (ared[2] + ared[3]);
    float mean = *loss / (float)((size_t)N * D);
    float cb = mean;
    float cm = mean;
    float vq = cb + 0.25f * cm;
    size_t base = (size_t)N * D;
    out[base + 0] = vq;
    out[base + 1] = cb;
    out[base + 2] = cm;
    out[base + 3 + N] = (float)exp(-e);
    out[base + 4 + N] = (float)a;
  }
}

extern "C" void kernel_launch(void* const* d_in, const int* in_sizes, int n_in,
                              void* d_out, int out_size, void* d_ws, size_t ws_size,
                              hipStream_t stream) {
  const float* z = (const float*)d_in[0];
  const float* emb = (const float*)d_in[1];
  float* out = (float*)d_out;

  char* w = (char*)d_ws;
  float* e2 = (float*)w;                         w += (size_t)K * sizeof(float);
  int* counts = (int*)w;                         w += (size_t)K * sizeof(int);
  float* loss = (float*)w;                       w += 256;  // keep alignment
  float* pbest = (float*)w;                      w += (size_t)S * N * sizeof(float);
  int* pidx = (int*)w;

  prep_kernel<<<K / 256, 256, 0, stream>>>(emb, e2, counts, loss);
  vq_scan<<<dim3(N / 256, S), 256, 0, stream>>>(z, emb, e2, pbest, pidx);
  vq_epilogue<<<N / 256, 256, 0, stream>>>(z, emb, pbest, pidx, out, counts, loss);
  finalize_kernel<<<1, 256, 0, stream>>>(counts, loss, out);
}

// Round 9
// 482.721 us; speedup vs baseline: 1.7478x; 1.0115x over previous
//
#include <hip/hip_runtime.h>

// VQ-VAE Vector Quantizer: N=65536 rows, K=4096 codes, D=64, fp32.
// R10 (resubmit — previous round was a broker timeout, kernel never ran):
// L1-warming prefetch. R9 == R7 (455us, VALU 72%) falsified the
// address-fat theory (compiler already uses saddr+imm, SALU bumps). Surviving
// model: all 16 waves/CU ride the same e-stream head; distance-1 bank refill
// gives ~150cy slack vs ~200-300cy L2 latency -> every wave stalls ~100cy
// every code = the 28% idle. Register-deepening the pipeline hits the
// 128-reg/4-wave cliff (R8 spilled). Fix: one extra global_load_dword per
// iteration at tid*4 into the stream 8 codes ahead (per-wave 256B = 1 code;
// block's 4 waves cover k+8..k+11) -> refills hit L1 (~40cy << slack).
// Dummy dest kept alive by an empty asm sink reading the PREVIOUS warm value
// (1 iter = ~350cy old: its waitcnt is a no-op partial wait, never a drain).
// Warm offset wraps within the 128KB slice (uniform cselect) -> no OOB.
// Cost: +2 VGPR, 1 VMEM/iter on an idle pipe. Data path byte-identical to R9.
// FMA sequence per (row,code) is bit-identical to the R0/R7/R9 passing
// kernels (quad-split partials by d mod 4, ascending d, (s0+s1)+(s2+s3),
// dist = (z2 + e2[k]) - 2*dot, strict < first-index tie-break) => identical
// indices, absmax 0 by construction.
//
// out layout (float): [0,N*D) z_q_st | [ND] vq | [ND+1] cb | [ND+2] cm |
//                     [ND+3, ND+3+N) indices | [ND+3+N] perplexity | [ND+4+N] active

constexpr int N = 65536;
constexpr int K = 4096;
constexpr int D = 64;
constexpr int S = 8;      // K-split: grid = 2048 blocks
constexpr int KS = K / S; // 512 codes per slice
constexpr int SLICE_BYTES = KS * D * 4;   // 131072
constexpr int WARM_AHEAD = 2048;          // 8 codes ahead
constexpr int WARM_WRAP = SLICE_BYTES - 1024;  // keep +tid*4 in-slice

__global__ __launch_bounds__(256) void prep_kernel(const float* __restrict__ emb,
                                                   float* __restrict__ e2,
                                                   int* __restrict__ counts,
                                                   float* __restrict__ loss) {
  int k = blockIdx.x * 256 + threadIdx.x;
  if (k < K) {
    const float4* ep = (const float4*)(emb + (size_t)k * D);
    float s0 = 0.f, s1 = 0.f, s2 = 0.f, s3 = 0.f;
#pragma unroll
    for (int i = 0; i < 16; ++i) {
      float4 e = ep[i];
      s0 = fmaf(e.x, e.x, s0);
      s1 = fmaf(e.y, e.y, s1);
      s2 = fmaf(e.z, e.z, s2);
      s3 = fmaf(e.w, e.w, s3);
    }
    e2[k] = (s0 + s1) + (s2 + s3);
    counts[k] = 0;
  }
  if (blockIdx.x == 0 && threadIdx.x == 0) *loss = 0.0f;
}

// Scan one K-slice for 256 rows per block. grid = (N/256, S). No LDS.
__global__ __launch_bounds__(256) void vq_scan(const float* __restrict__ z,
                                               const float* __restrict__ emb,
                                               const float* __restrict__ e2,
                                               float* __restrict__ pbest,
                                               int* __restrict__ pidx) {
  const int tid = threadIdx.x;
  const int n = blockIdx.x * 256 + tid;
  const int s = blockIdx.y;
  const int k0 = s * KS;

  // This lane's z row (register-resident on the unified file).
  float4 zr[16];
  {
    const float4* zp = (const float4*)(z + (size_t)n * D);
#pragma unroll
    for (int i = 0; i < 16; ++i) zr[i] = zp[i];
  }

  // z2, same instruction sequence as R0/R9 (quad-split by d mod 4, ascending d).
  float z2;
  {
    float s0 = 0.f, s1 = 0.f, s2 = 0.f, s3 = 0.f;
#pragma unroll
    for (int i = 0; i < 16; ++i) {
      s0 = fmaf(zr[i].x, zr[i].x, s0);
      s1 = fmaf(zr[i].y, zr[i].y, s1);
      s2 = fmaf(zr[i].z, zr[i].z, s2);
      s3 = fmaf(zr[i].w, zr[i].w, s3);
    }
    z2 = (s0 + s1) + (s2 + s3);
  }

  // Uniform slice base (SGPR) + running pointers; body loads use imm offsets.
  const char* sb = (const char*)(emb + (size_t)k0 * D);
  const float4* fc = (const float4*)sb;  // current code
  const float* e2c = e2 + k0;
  const int lane4 = tid * 4;             // per-lane warm offset (1 VGPR)
  float warm = 0.0f;                     // warm-load dummy dest (1 VGPR)

  // Prologue: preload code 0 into the two banks (f=0..7 -> rr, f=8..15 -> qq).
  float4 rr[8], qq[8];
#pragma unroll
  for (int j = 0; j < 8; ++j) rr[j] = fc[j];
#pragma unroll
  for (int j = 0; j < 8; ++j) qq[j] = fc[8 + j];
  float e2cur = e2c[0];

  float best = 3.4e38f;
  int bidx = k0;

  for (int k = 0; k < KS - 1; ++k) {
    float s0 = 0.f, s1 = 0.f, s2 = 0.f, s3 = 0.f;
    // Phase 1: consume rr (f=0..7 of code k), refill with code k+1.
    // Refill addresses: fc[16+j] -> imm offset 256+16j (folds, SALU bump).
#pragma unroll
    for (int j = 0; j < 8; ++j) {
      float4 e = rr[j];
      // d = 4*j + {0,1,2,3}; partial sN takes d%4==N, ascending d
      s0 = fmaf(zr[j].x, e.x, s0);
      s1 = fmaf(zr[j].y, e.y, s1);
      s2 = fmaf(zr[j].z, e.z, s2);
      s3 = fmaf(zr[j].w, e.w, s3);
      rr[j] = fc[16 + j];  // WAR: legal only after the FMAs above
    }
    float e2n = e2c[1];
    // Phase 2: consume qq (f=8..15 of code k), refill with code k+1.
#pragma unroll
    for (int j = 0; j < 8; ++j) {
      float4 e = qq[j];
      s0 = fmaf(zr[8 + j].x, e.x, s0);
      s1 = fmaf(zr[8 + j].y, e.y, s1);
      s2 = fmaf(zr[8 + j].z, e.z, s2);
      s3 = fmaf(zr[8 + j].w, e.w, s3);
      qq[j] = fc[24 + j];  // imm offset 384+16j
    }
    float dot = (s0 + s1) + (s2 + s3);
    float dist = (z2 + e2cur) - 2.0f * dot;  // reference fp32 rounding replicated
    if (dist < best) { best = dist; bidx = k0 + k; }  // strict <: first-index in slice
    e2cur = e2n;

    // L1-warming prefetch, 8 codes ahead, wrapped within the slice (uniform
    // SALU). Sink the PREVIOUS warm value (1 iter old -> its implied waitcnt
    // is a partial, already-satisfied wait), then overwrite with the new load.
    {
      int uoff = k * 256 + WARM_AHEAD;
      uoff = (uoff >= WARM_WRAP) ? (uoff - WARM_WRAP) : uoff;
      asm volatile("" :: "v"(warm));
      warm = *(const float*)(sb + uoff + lane4);
    }

    fc += 16;
    e2c += 1;
  }
  {
    // Final code (k = KS-1): identical FMA sequence, no refill, no warm.
    float s0 = 0.f, s1 = 0.f, s2 = 0.f, s3 = 0.f;
#pragma unroll
    for (int j = 0; j < 8; ++j) {
      float4 e = rr[j];
      s0 = fmaf(zr[j].x, e.x, s0);
      s1 = fmaf(zr[j].y, e.y, s1);
      s2 = fmaf(zr[j].z, e.z, s2);
      s3 = fmaf(zr[j].w, e.w, s3);
    }
#pragma unroll
    for (int j = 0; j < 8; ++j) {
      float4 e = qq[j];
      s0 = fmaf(zr[8 + j].x, e.x, s0);
      s1 = fmaf(zr[8 + j].y, e.y, s1);
      s2 = fmaf(zr[8 + j].z, e.z, s2);
      s3 = fmaf(zr[8 + j].w, e.w, s3);
    }
    float dot = (s0 + s1) + (s2 + s3);
    float dist = (z2 + e2cur) - 2.0f * dot;
    if (dist < best) { best = dist; bidx = k0 + KS - 1; }
    asm volatile("" :: "v"(warm));  // keep the last warm load alive
  }

  pbest[(size_t)s * N + n] = best;
  pidx[(size_t)s * N + n] = bidx;
}

// Combine slices (ascending s = ascending k => first-index tie-break preserved),
// then gather/losses/counts/index write.
__global__ __launch_bounds__(256) void vq_epilogue(const float* __restrict__ z,
                                                   const float* __restrict__ emb,
                                                   const float* __restrict__ pbest,
                                                   const int* __restrict__ pidx,
                                                   float* __restrict__ out,
                                                   int* __restrict__ counts,
                                                   float* __restrict__ loss) {
  __shared__ float red[4];
  const int tid = threadIdx.x;
  const int n = blockIdx.x * 256 + tid;

  float best = pbest[n];
  int bidx = pidx[n];
#pragma unroll
  for (int s = 1; s < S; ++s) {
    float d = pbest[(size_t)s * N + n];
    if (d < best) { best = d; bidx = pidx[(size_t)s * N + n]; }
  }

  out[(size_t)N * D + 3 + n] = (float)bidx;
  atomicAdd(&counts[bidx], 1);

  const float4* zp = (const float4*)(z + (size_t)n * D);
  const float4* qp = (const float4*)(emb + (size_t)bidx * D);
  float4* op = (float4*)(out + (size_t)n * D);
  float lsum = 0.f;
#pragma unroll
  for (int i = 0; i < 16; ++i) {
    float4 q = qp[i];
    float4 zz = zp[i];
    float dx = q.x - zz.x, dy = q.y - zz.y, dz = q.z - zz.z, dw = q.w - zz.w;
    lsum = fmaf(dx, dx, lsum);
    lsum = fmaf(dy, dy, lsum);
    lsum = fmaf(dz, dz, lsum);
    lsum = fmaf(dw, dw, lsum);
    // z_q_st = z + (z_q - z), replicated op-for-op
    float4 r;
    r.x = zz.x + dx; r.y = zz.y + dy; r.z = zz.z + dz; r.w = zz.w + dw;
    op[i] = r;
  }

#pragma unroll
  for (int off = 32; off > 0; off >>= 1) lsum += __shfl_down(lsum, off);
  if ((tid & 63) == 0) red[tid >> 6] = lsum;
  __syncthreads();
  if (tid == 0) atomicAdd(loss, (red[0] + red[1]) + (red[2] + red[3]));
}

__global__ __launch_bounds__(256) void finalize_kernel(const int* __restrict__ counts,
                                                       const float* __restrict__ loss,
                                                       float* __restrict__ out) {
  const int tid = threadIdx.x;
  double ent = 0.0;
  int active = 0;
  for (int k = tid; k < K; k += 256) {
    int c = counts[k];
    float p = (float)c / 65536.0f;
    if (c > 0) active++;
    ent += (double)(p * logf(p + 1e-10f));
  }
#pragma unroll
  for (int off = 32; off > 0; off >>= 1) {
    ent += __shfl_down(ent, off);
    active += __shfl_down(active, off);
  }
  __shared__ double ered[4];
  __shared__ int ared[4];
  if ((tid & 63) == 0) { ered[tid >> 6] = ent; ared[tid >> 6] = active; }
  __syncthreads();
  if (tid == 0) {
    double e = (ered[0] + ered[1]) + (ered[2] + ered[3]);
    int a = (ared[0] + ared[1]) + (ared[2] + ared[3]);
    float mean = *loss / (float)((size_t)N * D);
    float cb = mean;
    float cm = mean;
    float vq = cb + 0.25f * cm;
    size_t base = (size_t)N * D;
    out[base + 0] = vq;
    out[base + 1] = cb;
    out[base + 2] = cm;
    out[base + 3 + N] = (float)exp(-e);
    out[base + 4 + N] = (float)a;
  }
}

extern "C" void kernel_launch(void* const* d_in, const int* in_sizes, int n_in,
                              void* d_out, int out_size, void* d_ws, size_t ws_size,
                              hipStream_t stream) {
  const float* z = (const float*)d_in[0];
  const float* emb = (const float*)d_in[1];
  float* out = (float*)d_out;

  char* w = (char*)d_ws;
  float* e2 = (float*)w;                         w += (size_t)K * sizeof(float);
  int* counts = (int*)w;                         w += (size_t)K * sizeof(int);
  float* loss = (float*)w;                       w += 256;  // keep alignment
  float* pbest = (float*)w;                      w += (size_t)S * N * sizeof(float);
  int* pidx = (int*)w;

  prep_kernel<<<K / 256, 256, 0, stream>>>(emb, e2, counts, loss);
  vq_scan<<<dim3(N / 256, S), 256, 0, stream>>>(z, emb, e2, pbest, pidx);
  vq_epilogue<<<N / 256, 256, 0, stream>>>(z, emb, pbest, pidx, out, counts, loss);
  finalize_kernel<<<1, 256, 0, stream>>>(counts, loss, out);
}